// Round 8
// baseline (1627.822 us; speedup 1.0000x reference)
//
#include <hip/hip_runtime.h>
#include <hip/hip_bf16.h>

// Problem constants
#define T_TOKENS 8192   // SEQ*BS
#define H_DIM 2048
#define I_DIM 4096
#define E_EXP 8
#define PAD_ROWS 9216   // 8192 + 8*128 worst-case padded segment total

typedef __bf16 bf16x8 __attribute__((ext_vector_type(8)));
typedef float floatx4 __attribute__((ext_vector_type(4)));
typedef unsigned short ushort8 __attribute__((ext_vector_type(8)));

__device__ __forceinline__ unsigned short f2bf(float f) {
  // round-to-nearest-even f32 -> bf16 (inputs are finite; no NaN handling needed)
  union { float f; unsigned int i; } c; c.f = f;
  unsigned int x = c.i;
  unsigned int r = x + 0x7fffu + ((x >> 16) & 1u);
  return (unsigned short)(r >> 16);
}

__device__ __forceinline__ float bf2float(unsigned short u) {
  union { unsigned int i; float f; } c; c.i = ((unsigned int)u) << 16;
  return c.f;
}

// async global->LDS, 16B per lane. LDS dest = wave-uniform base + lane*16.
// Global source is PER-LANE (guide §5 / m173).
__device__ __forceinline__ void gload_lds16(const void* g, void* l) {
  __builtin_amdgcn_global_load_lds(
      (const __attribute__((address_space(1))) void*)g,
      (__attribute__((address_space(3))) void*)l, 16, 0, 0);
}

// ---------------------------------------------------------------------------
// K1: router logits + argmax + fused fp32->bf16 conversion of hidden.
// One wave per token; hidden read ONCE. hdr zeroed via hipMemsetAsync.
// ---------------------------------------------------------------------------
__global__ __launch_bounds__(256) void router_kernel(const float* __restrict__ x,
                                                     const float* __restrict__ rw,
                                                     unsigned short* __restrict__ xb,
                                                     int* __restrict__ idx,
                                                     int* __restrict__ hdr) {
  const int lane = threadIdx.x & 63;
  const int t = blockIdx.x * 4 + (threadIdx.x >> 6);
  const float* xr = x + (size_t)t * H_DIM;
  unsigned short* xbr = xb + (size_t)t * H_DIM;
  float acc[8];
#pragma unroll
  for (int e = 0; e < 8; ++e) acc[e] = 0.f;
#pragma unroll
  for (int j = 0; j < 8; ++j) {
    const int c0 = (lane + j * 64) * 4;
    floatx4 v = *(const floatx4*)(xr + c0);
    ushort4 o;
    o.x = f2bf(v[0]); o.y = f2bf(v[1]); o.z = f2bf(v[2]); o.w = f2bf(v[3]);
    *(ushort4*)(xbr + c0) = o;
#pragma unroll
    for (int cc = 0; cc < 4; ++cc) {
      const float h = v[cc];
      floatx4 r0 = *(const floatx4*)(rw + (size_t)(c0 + cc) * 8);
      floatx4 r1 = *(const floatx4*)(rw + (size_t)(c0 + cc) * 8 + 4);
#pragma unroll
      for (int e = 0; e < 4; ++e) { acc[e] += h * r0[e]; acc[e + 4] += h * r1[e]; }
    }
  }
#pragma unroll
  for (int off = 32; off > 0; off >>= 1)
#pragma unroll
    for (int e = 0; e < 8; ++e) acc[e] += __shfl_xor(acc[e], off, 64);
  if (lane == 0) {
    int best = 0; float bv = acc[0];
#pragma unroll
    for (int e = 1; e < 8; ++e) if (acc[e] > bv) { bv = acc[e]; best = e; }
    idx[t] = best;
    atomicAdd(&hdr[best], 1);
  }
}

// ---------------------------------------------------------------------------
// K2: segment bases (128-aligned) + rows[] sentinel init
// ---------------------------------------------------------------------------
__global__ __launch_bounds__(256) void setup_kernel(int* __restrict__ hdr,
                                                    int* __restrict__ rows) {
  if (threadIdx.x == 0) {
    int b = 0;
    for (int e = 0; e < 8; ++e) {
      hdr[16 + e] = b;
      b += ((hdr[e] + 127) >> 7) << 7;
    }
  }
  for (int i = threadIdx.x; i < PAD_ROWS; i += 256) rows[i] = -1;
}

// ---------------------------------------------------------------------------
// K3: scatter token ids into per-expert segments
// ---------------------------------------------------------------------------
__global__ __launch_bounds__(256) void scatter_kernel(const int* __restrict__ idx,
                                                      int* __restrict__ hdr,
                                                      int* __restrict__ rows) {
  int t = blockIdx.x * 256 + threadIdx.x;
  int e = idx[t];
  int p = atomicAdd(&hdr[8 + e], 1);
  rows[hdr[16 + e] + p] = t;
}

// ---------------------------------------------------------------------------
// K4a: ALL-IN-ONE weight prepass (big-workspace path). Chunk-tiled output
// [e][kg=k>>3][ng=n>>4][n&15][k&7]. Register transpose; 1KB/wave contiguous
// nontemporal reads (weights are read-once -> keep L2/L3 for bf16 outputs);
// 64B/thread contiguous writes (16KB contiguous per block).
// ---------------------------------------------------------------------------
__global__ __launch_bounds__(256) void cvt_all_kernel(const float* __restrict__ gw,
                                                      const float* __restrict__ uw,
                                                      const float* __restrict__ dw,
                                                      unsigned short* __restrict__ Wg,
                                                      unsigned short* __restrict__ Wu,
                                                      unsigned short* __restrict__ Wd) {
  int bid = blockIdx.x;
  const float* W; unsigned short* Wt; int K, N;
  if (bid < 16384) {
    W = (bid < 8192) ? gw : uw; Wt = (bid < 8192) ? Wg : Wu;
    K = H_DIM; N = I_DIM;
    bid &= 8191;
  } else {
    W = dw; Wt = Wd; K = I_DIM; N = H_DIM;
    bid -= 16384;
  }
  const int e = bid >> 10;
  const int rem = bid & 1023;
  const int nper = N >> 10;
  const int nbx = rem & (nper - 1);
  const int kg = rem / nper;
  const int nb = nbx * 1024;
  const int n0 = threadIdx.x * 4;
  const float* src = W + (size_t)e * K * N + (size_t)kg * 8 * N + nb + n0;
  unsigned short* dst = Wt + (size_t)e * K * N
                        + ((size_t)kg * (N >> 4) + (nb >> 4)) * 128;
  floatx4 a[8];
#pragma unroll
  for (int kk = 0; kk < 8; ++kk)
    a[kk] = __builtin_nontemporal_load((const floatx4*)(src + (size_t)kk * N));
#pragma unroll
  for (int nn = 0; nn < 4; ++nn) {
    const int n = n0 + nn;
    ushort8 o;
#pragma unroll
    for (int kk = 0; kk < 8; ++kk) o[kk] = f2bf(a[kk][nn]);
    *(ushort8*)(dst + (size_t)(n >> 4) * 128 + (n & 15) * 8) = o;
  }
}

// ---------------------------------------------------------------------------
// K4b: fallback (small workspace): gate+up merged; down converted after gu.
// ---------------------------------------------------------------------------
__global__ __launch_bounds__(256) void cvt_gu_kernel(const float* __restrict__ gw,
                                                     const float* __restrict__ uw,
                                                     unsigned short* __restrict__ Wg,
                                                     unsigned short* __restrict__ Wu) {
  const int z = blockIdx.z;
  const int e = z & 7;
  const float* W = (z < 8) ? gw : uw;
  unsigned short* Wt = (z < 8) ? Wg : Wu;
  const int kg = blockIdx.y;
  const int nb = blockIdx.x * 1024;
  const int n0 = threadIdx.x * 4;
  const float* src = W + (size_t)e * H_DIM * I_DIM + (size_t)kg * 8 * I_DIM + nb + n0;
  unsigned short* dst = Wt + (size_t)e * H_DIM * I_DIM
                        + ((size_t)kg * (I_DIM >> 4) + (nb >> 4)) * 128;
  floatx4 a[8];
#pragma unroll
  for (int kk = 0; kk < 8; ++kk)
    a[kk] = __builtin_nontemporal_load((const floatx4*)(src + (size_t)kk * I_DIM));
#pragma unroll
  for (int nn = 0; nn < 4; ++nn) {
    const int n = n0 + nn;
    ushort8 o;
#pragma unroll
    for (int kk = 0; kk < 8; ++kk) o[kk] = f2bf(a[kk][nn]);
    *(ushort8*)(dst + (size_t)(n >> 4) * 128 + (n & 15) * 8) = o;
  }
}

template <int K, int N>
__global__ __launch_bounds__(256) void cvt_tile_kernel(const float* __restrict__ W,
                                                       unsigned short* __restrict__ Wt) {
  const int e = blockIdx.z;
  const int kg = blockIdx.y;
  const int nb = blockIdx.x * 1024;
  const int n0 = threadIdx.x * 4;
  const float* src = W + (size_t)e * K * N + (size_t)kg * 8 * N + nb + n0;
  unsigned short* dst = Wt + (size_t)e * K * N
                        + ((size_t)kg * (N / 16) + (nb >> 4)) * 128;
  floatx4 a[8];
#pragma unroll
  for (int kk = 0; kk < 8; ++kk)
    a[kk] = __builtin_nontemporal_load((const floatx4*)(src + (size_t)kk * N));
#pragma unroll
  for (int nn = 0; nn < 4; ++nn) {
    const int n = n0 + nn;
    ushort8 o;
#pragma unroll
    for (int kk = 0; kk < 8; ++kk) o[kk] = f2bf(a[kk][nn]);
    *(ushort8*)(dst + (size_t)(n >> 4) * 128 + (n & 15) * 8) = o;
  }
}

// ---------------------------------------------------------------------------
// K5: fused gate+up grouped GEMM, COUNTED-VMCNT DOUBLE-BUFFERED (T3/T4-min).
// 128x128 tile, BK=32, 4 waves, dual acc (gate,up). Per k-tile: prefetch
// tile t+1 (6 gload_lds/thread) -> s_waitcnt vmcnt(6) (own-wave: waits only
// tile t's 6; t+1's stay IN FLIGHT across the barrier) -> barrier ->
// ds_read frags + 32 MFMA -> barrier. Never vmcnt(0) mid-loop (T4).
// LDS 2 x (A 8KB + Bg 8KB + Bu 8KB) = 48KB -> 3 blocks/CU.
// A LDS is slot-major [4 kslot][128 row][8]: DMA-linear writes, 256B-
// contiguous conflict-free ds_read_b128; gather needs 1 rows[] lookup/thread.
// B chunk-tiled [kg4][ng8][16][8] as before (conflict-free both sides).
// sched_barrier(0) after waitcnt asm per rule #18.
// ---------------------------------------------------------------------------
__global__ __launch_bounds__(256, 3) void moe_gemm_gu(
    const unsigned short* __restrict__ A,
    const unsigned short* __restrict__ Bg,
    const unsigned short* __restrict__ Bu,
    const int* __restrict__ hdr,
    const int* __restrict__ rows,
    unsigned short* __restrict__ inter) {
  const int e = blockIdx.z;
  const int cnt = hdr[e];
  if ((int)blockIdx.y * 128 >= cnt) return;  // uniform early exit
  const int seg = hdr[16 + e];

  const int tid = threadIdx.x;
  const int lane = tid & 63;
  const int wv = tid >> 6;
  const int wm = (wv & 1) * 64;
  const int wn = (wv >> 1) * 64;
  const int q = lane >> 4;
  const int l15 = lane & 15;

  __shared__ unsigned short sA[2][4096];   // [kslot4][row128][8]
  __shared__ unsigned short sBg[2][4096];  // [kg4][ng8][16][8]
  __shared__ unsigned short sBu[2][4096];

  // A gather: wave w instr i stages rows ((w&1)*64 + lane) into k-slot
  // (w>>1)+2i; one rows[] lookup per thread serves both instrs.
  const int Rst = (wv & 1) * 64 + lane;
  int ar = rows[seg + blockIdx.y * 128 + Rst];
  if (ar < 0) ar = 0;  // padding rows: junk compute, dropped downstream
  const unsigned short* aA = A + (size_t)ar * H_DIM;
  const int s0 = wv >> 1;          // k-slot (8 bf16) for instr 0
  const int dA0 = wv * 512;        // LDS ushort dest bases
  const int dA1 = (wv + 4) * 512;

  const int N16 = I_DIM / 16;
  const int ng0 = blockIdx.x * 8;
  const unsigned short* BgE = Bg + (size_t)e * I_DIM * H_DIM;
  const unsigned short* BuE = Bu + (size_t)e * I_DIM * H_DIM;

  floatx4 accg[4][4], accu[4][4];
#pragma unroll
  for (int a = 0; a < 4; ++a)
#pragma unroll
    for (int b = 0; b < 4; ++b) {
      accg[a][b] = (floatx4){0.f, 0.f, 0.f, 0.f};
      accu[a][b] = (floatx4){0.f, 0.f, 0.f, 0.f};
    }

  const int wn16 = wn >> 4;  // 0 or 4

#define STAGE_GU(buf, kt)                                                      \
  do {                                                                         \
    gload_lds16(aA + (kt) + s0 * 8, &sA[buf][dA0]);                            \
    gload_lds16(aA + (kt) + (s0 + 2) * 8, &sA[buf][dA1]);                      \
    const size_t bo = ((size_t)(((kt) >> 3) + wv) * N16 + ng0) * 128 + lane * 8;\
    gload_lds16(BgE + bo, &sBg[buf][wv * 1024]);                               \
    gload_lds16(BgE + bo + 512, &sBg[buf][wv * 1024 + 512]);                   \
    gload_lds16(BuE + bo, &sBu[buf][wv * 1024]);                               \
    gload_lds16(BuE + bo + 512, &sBu[buf][wv * 1024 + 512]);                   \
  } while (0)

  STAGE_GU(0, 0);
  for (int t = 0; t < 64; ++t) {
    if (t < 63) {
      STAGE_GU((t + 1) & 1, (t + 1) * 32);
      asm volatile("s_waitcnt vmcnt(6)" ::: "memory");
    } else {
      asm volatile("s_waitcnt vmcnt(0)" ::: "memory");
    }
    __builtin_amdgcn_sched_barrier(0);
    __builtin_amdgcn_s_barrier();
    const unsigned short* sAc = sA[t & 1];
    const unsigned short* sBgc = sBg[t & 1];
    const unsigned short* sBuc = sBu[t & 1];
    bf16x8 af[4], bfr[4];
#pragma unroll
    for (int fm = 0; fm < 4; ++fm)
      af[fm] = __builtin_bit_cast(bf16x8,
          *(const ushort8*)(sAc + q * 1024 + (wm + fm * 16 + l15) * 8));
#pragma unroll
    for (int fn = 0; fn < 4; ++fn)
      bfr[fn] = __builtin_bit_cast(bf16x8,
          *(const ushort8*)(sBgc + (q * 8 + wn16 + fn) * 128 + l15 * 8));
    __builtin_amdgcn_s_setprio(1);
#pragma unroll
    for (int fm = 0; fm < 4; ++fm)
#pragma unroll
      for (int fn = 0; fn < 4; ++fn)
        accg[fm][fn] = __builtin_amdgcn_mfma_f32_16x16x32_bf16(af[fm], bfr[fn],
                                                               accg[fm][fn], 0, 0, 0);
    __builtin_amdgcn_s_setprio(0);
#pragma unroll
    for (int fn = 0; fn < 4; ++fn)
      bfr[fn] = __builtin_bit_cast(bf16x8,
          *(const ushort8*)(sBuc + (q * 8 + wn16 + fn) * 128 + l15 * 8));
    __builtin_amdgcn_s_setprio(1);
#pragma unroll
    for (int fm = 0; fm < 4; ++fm)
#pragma unroll
      for (int fn = 0; fn < 4; ++fn)
        accu[fm][fn] = __builtin_amdgcn_mfma_f32_16x16x32_bf16(af[fm], bfr[fn],
                                                               accu[fm][fn], 0, 0, 0);
    __builtin_amdgcn_s_setprio(0);
    __builtin_amdgcn_sched_barrier(0);
    __builtin_amdgcn_s_barrier();
  }
#undef STAGE_GU

  // ---- epilogue: C/D layout col=lane&15, row=(lane>>4)*4+reg ----
#pragma unroll
  for (int fm = 0; fm < 4; ++fm)
#pragma unroll
    for (int fn = 0; fn < 4; ++fn)
#pragma unroll
      for (int rr = 0; rr < 4; ++rr) {
        const int row = wm + fm * 16 + q * 4 + rr;
        const int col = wn + fn * 16 + l15;
        const int gm = blockIdx.y * 128 + row;
        const int gn = blockIdx.x * 128 + col;
        const float g = accg[fm][fn][rr];
        const float u = accu[fm][fn][rr];
        const float s = g / (1.f + __expf(-g));  // silu in f32
        inter[(size_t)(seg + gm) * I_DIM + gn] = f2bf(s * u);
      }
}

// ---------------------------------------------------------------------------
// K6: down grouped GEMM, same counted-vmcnt dbuf structure; 128m x 256n
// (two B n-tiles), BK=32, scatters fp32 rows by token.
// ---------------------------------------------------------------------------
__global__ __launch_bounds__(256, 3) void moe_gemm_down(
    const unsigned short* __restrict__ A,
    const unsigned short* __restrict__ Bt,
    const int* __restrict__ hdr,
    const int* __restrict__ rows,
    float* __restrict__ outp) {
  const int e = blockIdx.z;
  const int cnt = hdr[e];
  if ((int)blockIdx.y * 128 >= cnt) return;  // uniform early exit
  const int seg = hdr[16 + e];

  const int tid = threadIdx.x;
  const int lane = tid & 63;
  const int wv = tid >> 6;
  const int wm = (wv & 1) * 64;
  const int wn = (wv >> 1) * 64;
  const int q = lane >> 4;
  const int l15 = lane & 15;

  __shared__ unsigned short sA[2][4096];
  __shared__ unsigned short sB0[2][4096];
  __shared__ unsigned short sB1[2][4096];

  const int Rst = (wv & 1) * 64 + lane;
  const unsigned short* aA = A + (size_t)(seg + blockIdx.y * 128 + Rst) * I_DIM;
  const int s0 = wv >> 1;
  const int dA0 = wv * 512;
  const int dA1 = (wv + 4) * 512;

  const int N16 = H_DIM / 16;
  const int ng0 = blockIdx.x * 16;
  const unsigned short* Be = Bt + (size_t)e * H_DIM * I_DIM;

  floatx4 acc0[4][4], acc1[4][4];
#pragma unroll
  for (int a = 0; a < 4; ++a)
#pragma unroll
    for (int b = 0; b < 4; ++b) {
      acc0[a][b] = (floatx4){0.f, 0.f, 0.f, 0.f};
      acc1[a][b] = (floatx4){0.f, 0.f, 0.f, 0.f};
    }

  const int wn16 = wn >> 4;

#define STAGE_DN(buf, kt)                                                      \
  do {                                                                         \
    gload_lds16(aA + (kt) + s0 * 8, &sA[buf][dA0]);                            \
    gload_lds16(aA + (kt) + (s0 + 2) * 8, &sA[buf][dA1]);                      \
    const size_t bo = ((size_t)(((kt) >> 3) + wv) * N16 + ng0) * 128 + lane * 8;\
    gload_lds16(Be + bo, &sB0[buf][wv * 1024]);                                \
    gload_lds16(Be + bo + 512, &sB0[buf][wv * 1024 + 512]);                    \
    gload_lds16(Be + bo + 1024, &sB1[buf][wv * 1024]);                         \
    gload_lds16(Be + bo + 1536, &sB1[buf][wv * 1024 + 512]);                   \
  } while (0)

  STAGE_DN(0, 0);
  for (int t = 0; t < 128; ++t) {
    if (t < 127) {
      STAGE_DN((t + 1) & 1, (t + 1) * 32);
      asm volatile("s_waitcnt vmcnt(6)" ::: "memory");
    } else {
      asm volatile("s_waitcnt vmcnt(0)" ::: "memory");
    }
    __builtin_amdgcn_sched_barrier(0);
    __builtin_amdgcn_s_barrier();
    const unsigned short* sAc = sA[t & 1];
    const unsigned short* sB0c = sB0[t & 1];
    const unsigned short* sB1c = sB1[t & 1];
    bf16x8 af[4], bfr[4];
#pragma unroll
    for (int fm = 0; fm < 4; ++fm)
      af[fm] = __builtin_bit_cast(bf16x8,
          *(const ushort8*)(sAc + q * 1024 + (wm + fm * 16 + l15) * 8));
#pragma unroll
    for (int fn = 0; fn < 4; ++fn)
      bfr[fn] = __builtin_bit_cast(bf16x8,
          *(const ushort8*)(sB0c + (q * 8 + wn16 + fn) * 128 + l15 * 8));
    __builtin_amdgcn_s_setprio(1);
#pragma unroll
    for (int fm = 0; fm < 4; ++fm)
#pragma unroll
      for (int fn = 0; fn < 4; ++fn)
        acc0[fm][fn] = __builtin_amdgcn_mfma_f32_16x16x32_bf16(af[fm], bfr[fn],
                                                               acc0[fm][fn], 0, 0, 0);
    __builtin_amdgcn_s_setprio(0);
#pragma unroll
    for (int fn = 0; fn < 4; ++fn)
      bfr[fn] = __builtin_bit_cast(bf16x8,
          *(const ushort8*)(sB1c + (q * 8 + wn16 + fn) * 128 + l15 * 8));
    __builtin_amdgcn_s_setprio(1);
#pragma unroll
    for (int fm = 0; fm < 4; ++fm)
#pragma unroll
      for (int fn = 0; fn < 4; ++fn)
        acc1[fm][fn] = __builtin_amdgcn_mfma_f32_16x16x32_bf16(af[fm], bfr[fn],
                                                               acc1[fm][fn], 0, 0, 0);
    __builtin_amdgcn_s_setprio(0);
    __builtin_amdgcn_sched_barrier(0);
    __builtin_amdgcn_s_barrier();
  }
#undef STAGE_DN

  // ---- epilogue: scatter both n-halves by token ----
#pragma unroll
  for (int fm = 0; fm < 4; ++fm)
#pragma unroll
    for (int rr = 0; rr < 4; ++rr) {
      const int row = wm + fm * 16 + q * 4 + rr;
      const int tok = rows[seg + blockIdx.y * 128 + row];
      if (tok < 0) continue;
      float* orow = outp + (size_t)tok * H_DIM + blockIdx.x * 256;
#pragma unroll
      for (int fn = 0; fn < 4; ++fn) {
        const int col = wn + fn * 16 + l15;
        orow[col]       = acc0[fm][fn][rr];
        orow[128 + col] = acc1[fm][fn][rr];
      }
    }
}

// ---------------------------------------------------------------------------
// host launcher
// ---------------------------------------------------------------------------
extern "C" void kernel_launch(void* const* d_in, const int* in_sizes, int n_in,
                              void* d_out, int out_size, void* d_ws, size_t ws_size,
                              hipStream_t stream) {
  const float* hidden   = (const float*)d_in[0];
  const float* router_w = (const float*)d_in[1];
  const float* gate_w   = (const float*)d_in[2];
  const float* up_w     = (const float*)d_in[3];
  const float* down_w   = (const float*)d_in[4];
  float* out = (float*)d_out;

  char* ws = (char*)d_ws;
  // ws layout (bytes):
  //   hdr   @ 0         : 32 ints
  //   idx   @ 1024      : 8192 ints            (32768 B)
  //   rows  @ 33792     : 9216 ints            (36864 B)
  //   x_bf  @ 70656     : 8192*2048 bf16       (33554432 B)
  //   inter @ 33625088  : 9216*4096 bf16       (75497472 B)
  //   W1    @ 109122560 : 134217728 B  (gate tiled; fallback: then down tiled)
  //   W2    @ 243340288 : 134217728 B  (up tiled)
  //   W3    @ 377558016 : 134217728 B  (down tiled -- big-ws path only)
  //   big total = 511775744 B; fallback total = 377558016 B
  int* hdr  = (int*)ws;
  int* idx  = (int*)(ws + 1024);
  int* rows = (int*)(ws + 33792);
  unsigned short* x_bf  = (unsigned short*)(ws + 70656);
  unsigned short* inter = (unsigned short*)(ws + 33625088);
  unsigned short* W1    = (unsigned short*)(ws + 109122560);
  unsigned short* W2    = (unsigned short*)(ws + 243340288);
  unsigned short* W3    = (unsigned short*)(ws + 377558016);
  const bool big = ws_size >= 511775744ull;

  hipMemsetAsync(hdr, 0, 128, stream);
  router_kernel<<<T_TOKENS / 4, 256, 0, stream>>>(hidden, router_w, x_bf, idx, hdr);
  setup_kernel<<<1, 256, 0, stream>>>(hdr, rows);
  scatter_kernel<<<T_TOKENS / 256, 256, 0, stream>>>(idx, hdr, rows);

  if (big) {
    cvt_all_kernel<<<24576, 256, 0, stream>>>(gate_w, up_w, down_w, W1, W2, W3);
    moe_gemm_gu<<<dim3(I_DIM / 128, 64, E_EXP), 256, 0, stream>>>(
        x_bf, W1, W2, hdr, rows, inter);
    moe_gemm_down<<<dim3(H_DIM / 256, 64, E_EXP), 256, 0, stream>>>(
        inter, W3, hdr, rows, out);
  } else {
    cvt_gu_kernel<<<dim3(4, 256, 16), 256, 0, stream>>>(gate_w, up_w, W1, W2);
    moe_gemm_gu<<<dim3(I_DIM / 128, 64, E_EXP), 256, 0, stream>>>(
        x_bf, W1, W2, hdr, rows, inter);
    cvt_tile_kernel<I_DIM, H_DIM><<<dim3(2, 512, 8), 256, 0, stream>>>(down_w, W1);
    moe_gemm_down<<<dim3(H_DIM / 256, 64, E_EXP), 256, 0, stream>>>(
        inter, W1, hdr, rows, out);
  }
}

// Round 9
// 1446.919 us; speedup vs baseline: 1.1250x; 1.1250x over previous
//
#include <hip/hip_runtime.h>
#include <hip/hip_bf16.h>

// Problem constants
#define T_TOKENS 8192   // SEQ*BS
#define H_DIM 2048
#define I_DIM 4096
#define E_EXP 8
#define PAD_ROWS 9216   // 8192 + 8*128 worst-case padded segment total

typedef __bf16 bf16x8 __attribute__((ext_vector_type(8)));
typedef float floatx4 __attribute__((ext_vector_type(4)));
typedef unsigned short ushort8 __attribute__((ext_vector_type(8)));

__device__ __forceinline__ unsigned short f2bf(float f) {
  // round-to-nearest-even f32 -> bf16 (inputs are finite; no NaN handling needed)
  union { float f; unsigned int i; } c; c.f = f;
  unsigned int x = c.i;
  unsigned int r = x + 0x7fffu + ((x >> 16) & 1u);
  return (unsigned short)(r >> 16);
}

__device__ __forceinline__ float bf2float(unsigned short u) {
  union { unsigned int i; float f; } c; c.i = ((unsigned int)u) << 16;
  return c.f;
}

// async global->LDS, 16B per lane. LDS dest = wave-uniform base + lane*16.
// Global source is PER-LANE (guide §5 / m173).
__device__ __forceinline__ void gload_lds16(const void* g, void* l) {
  __builtin_amdgcn_global_load_lds(
      (const __attribute__((address_space(1))) void*)g,
      (__attribute__((address_space(3))) void*)l, 16, 0, 0);
}

// ---------------------------------------------------------------------------
// cvt helper: one block converts an 8k x 1024n slab of fp32 W[K][N] into the
// chunk-tiled bf16 layout [kg=k>>3][ng=n>>4][n&15][k&7] (chunk = 256B).
// Reads 1KB/wave contiguous (nontemporal: weights are read-once); register
// transpose (static indices); 64B/thread contiguous writes (16KB/block).
// ---------------------------------------------------------------------------
__device__ __forceinline__ void cvt_slab(const float* __restrict__ W,
                                         unsigned short* __restrict__ Wt,
                                         int K, int N, int e, int kg, int nb,
                                         int tid) {
  const int n0 = tid * 4;
  const float* src = W + (size_t)e * K * N + (size_t)kg * 8 * N + nb + n0;
  unsigned short* dst = Wt + (size_t)e * K * N
                        + ((size_t)kg * (N >> 4) + (nb >> 4)) * 128;
  floatx4 a[8];
#pragma unroll
  for (int kk = 0; kk < 8; ++kk)
    a[kk] = __builtin_nontemporal_load((const floatx4*)(src + (size_t)kk * N));
#pragma unroll
  for (int nn = 0; nn < 4; ++nn) {
    const int n = n0 + nn;
    ushort8 o;
#pragma unroll
    for (int kk = 0; kk < 8; ++kk) o[kk] = f2bf(a[kk][nn]);
    *(ushort8*)(dst + (size_t)(n >> 4) * 128 + (n & 15) * 8) = o;
  }
}

// ---------------------------------------------------------------------------
// K1: MEGA pre-pass: router(+x cvt) blocks 0..2047, gate-cvt 2048..10239,
// up-cvt 10240..18431. These three jobs are mutually independent; fusing
// them into one dispatch runs them CONCURRENTLY (previously serialized).
// Router part: one wave per token, hidden read once, fused fp32->bf16 x_bf.
// hdr zeroed via hipMemsetAsync before this kernel.
// ---------------------------------------------------------------------------
__global__ __launch_bounds__(256) void router_cvt_kernel(
    const float* __restrict__ x, const float* __restrict__ rw,
    const float* __restrict__ gw, const float* __restrict__ uw,
    unsigned short* __restrict__ xb, int* __restrict__ idx,
    int* __restrict__ hdr, unsigned short* __restrict__ Wg,
    unsigned short* __restrict__ Wu) {
  if (blockIdx.x >= 2048) {
    // ---- weight-cvt branch (gate / up): K=H_DIM, N=I_DIM, nper = 4 ----
    int bid = blockIdx.x - 2048;
    const float* W = (bid < 8192) ? gw : uw;
    unsigned short* Wt = (bid < 8192) ? Wg : Wu;
    bid &= 8191;
    const int e = bid >> 10;
    const int rem = bid & 1023;
    cvt_slab(W, Wt, H_DIM, I_DIM, e, rem >> 2, (rem & 3) * 1024, threadIdx.x);
    return;
  }
  // ---- router branch ----
  const int lane = threadIdx.x & 63;
  const int t = blockIdx.x * 4 + (threadIdx.x >> 6);
  const float* xr = x + (size_t)t * H_DIM;
  unsigned short* xbr = xb + (size_t)t * H_DIM;
  float acc[8];
#pragma unroll
  for (int e = 0; e < 8; ++e) acc[e] = 0.f;
#pragma unroll
  for (int j = 0; j < 8; ++j) {
    const int c0 = (lane + j * 64) * 4;
    floatx4 v = *(const floatx4*)(xr + c0);
    ushort4 o;
    o.x = f2bf(v[0]); o.y = f2bf(v[1]); o.z = f2bf(v[2]); o.w = f2bf(v[3]);
    *(ushort4*)(xbr + c0) = o;
#pragma unroll
    for (int cc = 0; cc < 4; ++cc) {
      const float h = v[cc];
      floatx4 r0 = *(const floatx4*)(rw + (size_t)(c0 + cc) * 8);
      floatx4 r1 = *(const floatx4*)(rw + (size_t)(c0 + cc) * 8 + 4);
#pragma unroll
      for (int e = 0; e < 4; ++e) { acc[e] += h * r0[e]; acc[e + 4] += h * r1[e]; }
    }
  }
#pragma unroll
  for (int off = 32; off > 0; off >>= 1)
#pragma unroll
    for (int e = 0; e < 8; ++e) acc[e] += __shfl_xor(acc[e], off, 64);
  if (lane == 0) {
    int best = 0; float bv = acc[0];
#pragma unroll
    for (int e = 1; e < 8; ++e) if (acc[e] > bv) { bv = acc[e]; best = e; }
    idx[t] = best;
    atomicAdd(&hdr[best], 1);
  }
}

// ---------------------------------------------------------------------------
// K2: segment bases (128-aligned) + rows[] sentinel init
// ---------------------------------------------------------------------------
__global__ __launch_bounds__(256) void setup_kernel(int* __restrict__ hdr,
                                                    int* __restrict__ rows) {
  if (threadIdx.x == 0) {
    int b = 0;
    for (int e = 0; e < 8; ++e) {
      hdr[16 + e] = b;
      b += ((hdr[e] + 127) >> 7) << 7;
    }
  }
  for (int i = threadIdx.x; i < PAD_ROWS; i += 256) rows[i] = -1;
}

// ---------------------------------------------------------------------------
// K3: scatter token ids into per-expert segments
// ---------------------------------------------------------------------------
__global__ __launch_bounds__(256) void scatter_kernel(const int* __restrict__ idx,
                                                      int* __restrict__ hdr,
                                                      int* __restrict__ rows) {
  int t = blockIdx.x * 256 + threadIdx.x;
  int e = idx[t];
  int p = atomicAdd(&hdr[8 + e], 1);
  rows[hdr[16 + e] + p] = t;
}

// ---------------------------------------------------------------------------
// K4: fallback down-weight cvt (small ws: W3 absent; runs after gu, into W1)
// ---------------------------------------------------------------------------
__global__ __launch_bounds__(256) void cvt_down_kernel(const float* __restrict__ W,
                                                       unsigned short* __restrict__ Wt) {
  const int bid = blockIdx.x;          // 0..8191
  const int e = bid >> 10;
  const int rem = bid & 1023;
  cvt_slab(W, Wt, I_DIM, H_DIM, e, rem >> 1, (rem & 1) * 1024, threadIdx.x);
}

// ---------------------------------------------------------------------------
// K5: fused gate+up grouped GEMM (round-7 structure, proven 352us/780TF).
// 128x128 tile, BK=64, 4 waves, dual acc; A staged once, both B staged ->
// 64 MFMA per barrier pair. Epilogue: inter = silu(g_f32) * u.
// A staging: global_load_lds w16, XOR-swizzled via pre-swizzled SOURCE.
// B staging: chunk-tiled source -> lane-LINEAR 1KB DMA runs; B frag =
// conflict-free ds_read_b128 (k-contiguous by construction).
// EXTRA (big-ws): blockIdx.y in 64..95 = down-weight cvt blocks fused into
// this dispatch — they overlap gu's barrier-stall slack (gu uses <1 TB/s of
// HBM); W3 is only read by the LATER down dispatch (stream-ordered, safe).
// ---------------------------------------------------------------------------
__global__ __launch_bounds__(256, 2) void moe_gemm_gu(
    const unsigned short* __restrict__ A,
    const unsigned short* __restrict__ Bg,
    const unsigned short* __restrict__ Bu,
    const int* __restrict__ hdr,
    const int* __restrict__ rows,
    unsigned short* __restrict__ inter,
    const float* __restrict__ dw,
    unsigned short* __restrict__ Wd) {
  if (blockIdx.y >= 64) {
    // ---- fused down-weight cvt: K=I_DIM, N=H_DIM, nper = 2 ----
    const int cid = (((int)blockIdx.y - 64) * 32 + (int)blockIdx.x) * 8 + (int)blockIdx.z;
    const int e = cid >> 10;
    const int rem = cid & 1023;
    cvt_slab(dw, Wd, I_DIM, H_DIM, e, rem >> 1, (rem & 1) * 1024, threadIdx.x);
    return;
  }
  const int e = blockIdx.z;
  const int cnt = hdr[e];
  if ((int)blockIdx.y * 128 >= cnt) return;  // uniform early exit
  const int seg = hdr[16 + e];

  const int tid = threadIdx.x;
  const int lane = tid & 63;
  const int wv = tid >> 6;
  const int wm = (wv & 1) * 64;
  const int wn = (wv >> 1) * 64;
  const int q = lane >> 4;
  const int l15 = lane & 15;

  __shared__ unsigned short sA[128 * 64];   // [m][64k], slot-swizzled
  __shared__ unsigned short sBg[64 * 128];  // chunk-tiled [8kg][8ng][16][8]
  __shared__ unsigned short sBu[64 * 128];

  const int lr = lane >> 3;            // row within 8-row chunk == row&7
  const int colsw = (lane & 7) ^ lr;   // pre-swizzled 8-elem slot index
  const unsigned short* aptr[4];
#pragma unroll
  for (int j = 0; j < 4; ++j) {
    const int R = j * 32 + wv * 8 + lr;
    int ar = rows[seg + blockIdx.y * 128 + R];
    if (ar < 0) ar = 0;  // padding rows: junk compute, dropped downstream
    aptr[j] = A + (size_t)ar * H_DIM + colsw * 8;
  }

  const int N16 = I_DIM / 16;  // 256 chunks per kg row
  const int ng0 = blockIdx.x * 8;
  const unsigned short* BgE = Bg + (size_t)e * I_DIM * H_DIM;
  const unsigned short* BuE = Bu + (size_t)e * I_DIM * H_DIM;

  floatx4 accg[4][4], accu[4][4];
#pragma unroll
  for (int a = 0; a < 4; ++a)
#pragma unroll
    for (int b = 0; b < 4; ++b) {
      accg[a][b] = (floatx4){0.f, 0.f, 0.f, 0.f};
      accu[a][b] = (floatx4){0.f, 0.f, 0.f, 0.f};
    }

  const int ubB = q * 1024 + l15 * 8;       // ushort off: quadrant + row
  const int wn16o = (wn >> 4) * 128;        // 0 or 512

  for (int kt = 0; kt < H_DIM; kt += 64) {
#pragma unroll
    for (int j = 0; j < 4; ++j) {
      gload_lds16(aptr[j] + kt, sA + (j * 32 + wv * 8) * 64);
      const int g = j * 4 + wv;                        // 0..15 chunk-quad
      const int kgg = (kt >> 3) + (g >> 1);            // global kg
      const size_t so = (size_t)(kgg * N16 + ng0 + (g & 1) * 4) * 128 + lane * 8;
      gload_lds16(BgE + so, sBg + g * 512);
      gload_lds16(BuE + so, sBu + g * 512);
    }
    __syncthreads();  // vmcnt(0): DMA complete for all waves
#pragma unroll
    for (int ks = 0; ks < 64; ks += 32) {
      const int sbase = ks >> 3;
      const int bbase = ks * 128 + wn16o + ubB;
      bf16x8 af[4], bfr[4];
#pragma unroll
      for (int fm = 0; fm < 4; ++fm) {
        const int ra = wm + fm * 16 + l15;
        af[fm] = __builtin_bit_cast(bf16x8,
            *(const ushort8*)(sA + ra * 64 + (((q + sbase) ^ (ra & 7)) << 3)));
      }
#pragma unroll
      for (int fn = 0; fn < 4; ++fn)
        bfr[fn] = __builtin_bit_cast(bf16x8,
            *(const ushort8*)(sBg + bbase + fn * 128));
#pragma unroll
      for (int fm = 0; fm < 4; ++fm)
#pragma unroll
        for (int fn = 0; fn < 4; ++fn)
          accg[fm][fn] = __builtin_amdgcn_mfma_f32_16x16x32_bf16(af[fm], bfr[fn],
                                                                 accg[fm][fn], 0, 0, 0);
#pragma unroll
      for (int fn = 0; fn < 4; ++fn)
        bfr[fn] = __builtin_bit_cast(bf16x8,
            *(const ushort8*)(sBu + bbase + fn * 128));
#pragma unroll
      for (int fm = 0; fm < 4; ++fm)
#pragma unroll
        for (int fn = 0; fn < 4; ++fn)
          accu[fm][fn] = __builtin_amdgcn_mfma_f32_16x16x32_bf16(af[fm], bfr[fn],
                                                                 accu[fm][fn], 0, 0, 0);
    }
    __syncthreads();
  }

#pragma unroll
  for (int fm = 0; fm < 4; ++fm)
#pragma unroll
    for (int fn = 0; fn < 4; ++fn)
#pragma unroll
      for (int rr = 0; rr < 4; ++rr) {
        const int row = wm + fm * 16 + q * 4 + rr;
        const int col = wn + fn * 16 + l15;
        const int gm = blockIdx.y * 128 + row;
        const int gn = blockIdx.x * 128 + col;
        const float g = accg[fm][fn][rr];
        const float u = accu[fm][fn][rr];
        const float s = g / (1.f + __expf(-g));  // silu in f32
        inter[(size_t)(seg + gm) * I_DIM + gn] = f2bf(s * u);
      }
}

// ---------------------------------------------------------------------------
// K6: down grouped GEMM (round-7 structure), 2-way n-fusion: 128m x 256n.
// A = inter bf16 [PAD_ROWS][I_DIM]; Bt = chunk-tiled [E][K/8][N/16][16][8]
// (K=I_DIM, N=H_DIM). Scatters fp32 rows to outp by token.
// ---------------------------------------------------------------------------
__global__ __launch_bounds__(256, 2) void moe_gemm_down(
    const unsigned short* __restrict__ A,
    const unsigned short* __restrict__ Bt,
    const int* __restrict__ hdr,
    const int* __restrict__ rows,
    float* __restrict__ outp) {
  const int e = blockIdx.z;
  const int cnt = hdr[e];
  if ((int)blockIdx.y * 128 >= cnt) return;  // uniform early exit
  const int seg = hdr[16 + e];

  const int tid = threadIdx.x;
  const int lane = tid & 63;
  const int wv = tid >> 6;
  const int wm = (wv & 1) * 64;
  const int wn = (wv >> 1) * 64;
  const int q = lane >> 4;
  const int l15 = lane & 15;

  __shared__ unsigned short sA[128 * 64];
  __shared__ unsigned short sB0[64 * 128];
  __shared__ unsigned short sB1[64 * 128];

  const int lr = lane >> 3;
  const int colsw = (lane & 7) ^ lr;
  const unsigned short* aptr[4];
#pragma unroll
  for (int j = 0; j < 4; ++j) {
    const int R = j * 32 + wv * 8 + lr;
    aptr[j] = A + (size_t)(seg + blockIdx.y * 128 + R) * I_DIM + colsw * 8;
  }

  const int N16 = H_DIM / 16;  // 128 chunks per kg row
  const int ng0 = blockIdx.x * 16;
  const unsigned short* Be = Bt + (size_t)e * H_DIM * I_DIM;

  floatx4 acc0[4][4], acc1[4][4];
#pragma unroll
  for (int a = 0; a < 4; ++a)
#pragma unroll
    for (int b = 0; b < 4; ++b) {
      acc0[a][b] = (floatx4){0.f, 0.f, 0.f, 0.f};
      acc1[a][b] = (floatx4){0.f, 0.f, 0.f, 0.f};
    }

  const int ubB = q * 1024 + l15 * 8;
  const int wn16o = (wn >> 4) * 128;

  for (int kt = 0; kt < I_DIM; kt += 64) {
#pragma unroll
    for (int j = 0; j < 4; ++j) {
      gload_lds16(aptr[j] + kt, sA + (j * 32 + wv * 8) * 64);
      const int g = j * 4 + wv;
      const int kgg = (kt >> 3) + (g >> 1);
      const size_t so0 = (size_t)(kgg * N16 + ng0 + (g & 1) * 4) * 128 + lane * 8;
      const size_t so1 = (size_t)(kgg * N16 + ng0 + 8 + (g & 1) * 4) * 128 + lane * 8;
      gload_lds16(Be + so0, sB0 + g * 512);
      gload_lds16(Be + so1, sB1 + g * 512);
    }
    __syncthreads();
#pragma unroll
    for (int ks = 0; ks < 64; ks += 32) {
      const int sbase = ks >> 3;
      const int bbase = ks * 128 + wn16o + ubB;
      bf16x8 af[4], bfr[4];
#pragma unroll
      for (int fm = 0; fm < 4; ++fm) {
        const int ra = wm + fm * 16 + l15;
        af[fm] = __builtin_bit_cast(bf16x8,
            *(const ushort8*)(sA + ra * 64 + (((q + sbase) ^ (ra & 7)) << 3)));
      }
#pragma unroll
      for (int fn = 0; fn < 4; ++fn)
        bfr[fn] = __builtin_bit_cast(bf16x8,
            *(const ushort8*)(sB0 + bbase + fn * 128));
#pragma unroll
      for (int fm = 0; fm < 4; ++fm)
#pragma unroll
        for (int fn = 0; fn < 4; ++fn)
          acc0[fm][fn] = __builtin_amdgcn_mfma_f32_16x16x32_bf16(af[fm], bfr[fn],
                                                                 acc0[fm][fn], 0, 0, 0);
#pragma unroll
      for (int fn = 0; fn < 4; ++fn)
        bfr[fn] = __builtin_bit_cast(bf16x8,
            *(const ushort8*)(sB1 + bbase + fn * 128));
#pragma unroll
      for (int fm = 0; fm < 4; ++fm)
#pragma unroll
        for (int fn = 0; fn < 4; ++fn)
          acc1[fm][fn] = __builtin_amdgcn_mfma_f32_16x16x32_bf16(af[fm], bfr[fn],
                                                                 acc1[fm][fn], 0, 0, 0);
    }
    __syncthreads();
  }

#pragma unroll
  for (int fm = 0; fm < 4; ++fm)
#pragma unroll
    for (int rr = 0; rr < 4; ++rr) {
      const int row = wm + fm * 16 + q * 4 + rr;
      const int tok = rows[seg + blockIdx.y * 128 + row];
      if (tok < 0) continue;
      float* orow = outp + (size_t)tok * H_DIM + blockIdx.x * 256;
#pragma unroll
      for (int fn = 0; fn < 4; ++fn) {
        const int col = wn + fn * 16 + l15;
        orow[col]       = acc0[fm][fn][rr];
        orow[128 + col] = acc1[fm][fn][rr];
      }
    }
}

// ---------------------------------------------------------------------------
// host launcher
// ---------------------------------------------------------------------------
extern "C" void kernel_launch(void* const* d_in, const int* in_sizes, int n_in,
                              void* d_out, int out_size, void* d_ws, size_t ws_size,
                              hipStream_t stream) {
  const float* hidden   = (const float*)d_in[0];
  const float* router_w = (const float*)d_in[1];
  const float* gate_w   = (const float*)d_in[2];
  const float* up_w     = (const float*)d_in[3];
  const float* down_w   = (const float*)d_in[4];
  float* out = (float*)d_out;

  char* ws = (char*)d_ws;
  // ws layout (bytes):
  //   hdr   @ 0         : 32 ints
  //   idx   @ 1024      : 8192 ints            (32768 B)
  //   rows  @ 33792     : 9216 ints            (36864 B)
  //   x_bf  @ 70656     : 8192*2048 bf16       (33554432 B)
  //   inter @ 33625088  : 9216*4096 bf16       (75497472 B)
  //   W1    @ 109122560 : 134217728 B  (gate tiled; fallback: then down tiled)
  //   W2    @ 243340288 : 134217728 B  (up tiled)
  //   W3    @ 377558016 : 134217728 B  (down tiled -- big-ws path only)
  //   big total = 511775744 B; fallback total = 377558016 B
  int* hdr  = (int*)ws;
  int* idx  = (int*)(ws + 1024);
  int* rows = (int*)(ws + 33792);
  unsigned short* x_bf  = (unsigned short*)(ws + 70656);
  unsigned short* inter = (unsigned short*)(ws + 33625088);
  unsigned short* W1    = (unsigned short*)(ws + 109122560);
  unsigned short* W2    = (unsigned short*)(ws + 243340288);
  unsigned short* W3    = (unsigned short*)(ws + 377558016);
  const bool big = ws_size >= 511775744ull;

  hipMemsetAsync(hdr, 0, 128, stream);
  // mega pre-pass: router + gate-cvt + up-cvt run concurrently
  router_cvt_kernel<<<2048 + 16384, 256, 0, stream>>>(
      hidden, router_w, gate_w, up_w, x_bf, idx, hdr, W1, W2);
  setup_kernel<<<1, 256, 0, stream>>>(hdr, rows);
  scatter_kernel<<<T_TOKENS / 256, 256, 0, stream>>>(idx, hdr, rows);

  if (big) {
    // gu GEMM with down-weight cvt fused into extra y-rows (overlaps slack)
    moe_gemm_gu<<<dim3(I_DIM / 128, 96, E_EXP), 256, 0, stream>>>(
        x_bf, W1, W2, hdr, rows, inter, down_w, W3);
    moe_gemm_down<<<dim3(H_DIM / 256, 64, E_EXP), 256, 0, stream>>>(
        inter, W3, hdr, rows, out);
  } else {
    moe_gemm_gu<<<dim3(I_DIM / 128, 64, E_EXP), 256, 0, stream>>>(
        x_bf, W1, W2, hdr, rows, inter, nullptr, nullptr);
    cvt_down_kernel<<<8192, 256, 0, stream>>>(down_w, W1);
    moe_gemm_down<<<dim3(H_DIM / 256, 64, E_EXP), 256, 0, stream>>>(
        inter, W1, hdr, rows, out);
  }
}